// Round 1
// baseline (844.634 us; speedup 1.0000x reference)
//
#include <hip/hip_runtime.h>
#include <hip/hip_bf16.h>

// BayesianKAN: 3 layers of  out[b,o] = sum_{i,k} B-spline-basis(x[b,i])[k] * cm[o,i,k]
// == GEMM (M=8192, N=OUT, K=IN*16) with generated A-operand, plus KL scalar.
// Numerics: downstream amplification ~130x forces split-bf16 (3-term) MFMA for
// layers 0/1; layer 2 (no amplification of its own noise) runs plain bf16.

typedef __attribute__((ext_vector_type(8))) short short8;   // 8 bf16 in 4 VGPRs
typedef __attribute__((ext_vector_type(4))) float float4v;  // MFMA accumulator
typedef unsigned short ushort_t;

__device__ __forceinline__ ushort_t f2bf(float f) {
  unsigned u = __float_as_uint(f);
  u += 0x7fffu + ((u >> 16) & 1u);          // round-to-nearest-even
  return (ushort_t)(u >> 16);
}
__device__ __forceinline__ float bf2f(ushort_t h) {
  return __uint_as_float(((unsigned)h) << 16);
}

// Cubic B-spline (n_basis=16, clamped uniform knots: 13 cells of width 1/13).
// Returns first nonzero basis index k0 = cell and the 4 weights (basis funs alg,
// denominators are integer multiples of 1/13 -> select-based inverse, no divides).
__device__ __forceinline__ void bspline_w4(float x, int& k0, float w[4]) {
  const float XMAX = 1.0f - 1e-6f;
  float xe = fminf(fmaxf(x, 0.0f), XMAX);
  int cell = (int)(xe * 13.0f);
  cell = cell > 12 ? 12 : cell;
  k0 = cell;
  int j = cell + 3;                 // knot span, 3..15
  const float s = 1.0f / 13.0f;
  // knot(idx) = clamp(idx-3, 0, 13)/13 ; need idx = j-2 .. j+3
  int cjm2 = max(j - 5, 0);
  int cjm1 = max(j - 4, 0);
  int cj   = j - 3;
  int cj1  = j - 2;
  int cj2  = min(j - 1, 13);
  int cj3  = min(j, 13);
  float tjm2 = cjm2 * s, tjm1 = cjm1 * s, tj = cj * s;
  float tj1 = cj1 * s, tj2 = cj2 * s, tj3 = cj3 * s;
  float left1 = xe - tj, left2 = xe - tjm1, left3 = xe - tjm2;
  float right1 = tj1 - xe, right2 = tj2 - xe, right3 = tj3 - xe;
#define INV3(d) ((d) == 1 ? 13.0f : ((d) == 2 ? 6.5f : (13.0f / 3.0f)))
  float i10 = INV3(cj1 - cj);
  float i20 = INV3(cj1 - cjm1), i21 = INV3(cj2 - cj);
  float i30 = INV3(cj1 - cjm2), i31 = INV3(cj2 - cjm1), i32 = INV3(cj3 - cj);
#undef INV3
  // degree 1
  float temp = i10;                 // N0(=1) * i10
  float N0 = right1 * temp;
  float N1 = left1 * temp;
  // degree 2
  temp = N0 * i20;
  N0 = right1 * temp;
  float saved = left2 * temp;
  temp = N1 * i21;
  N1 = saved + right2 * temp;
  float N2 = left1 * temp;
  // degree 3
  temp = N0 * i30;
  N0 = right1 * temp;
  saved = left3 * temp;
  temp = N1 * i31;
  N1 = saved + right2 * temp;
  saved = left2 * temp;
  temp = N2 * i32;
  N2 = saved + right3 * temp;
  float N3 = left1 * temp;
  w[0] = N0; w[1] = N1; w[2] = N2; w[3] = N3;
}

// Fused basis-gen + GEMM. Tile 128x128, BK=64 (= 4 input features * 16 basis),
// 256 threads = 4 waves (2x2), wave tile 64x64 (4x4 frags of 16x16x32 bf16).
// NTERMS=3: split-bf16 (ah*bh + ah*bl + al*bh). NTERMS=1: plain bf16.
template <int NTERMS>
__global__ __launch_bounds__(256) void kan_layer(
    const float* __restrict__ act, const ushort_t* __restrict__ cmh,
    const ushort_t* __restrict__ cml, float* __restrict__ outp,
    int IN, int OUT) {
  const int K = IN * 16;
  __shared__ ushort_t Ah[128 * 72];                      // +8 pad: conflict-free b128 reads
  __shared__ ushort_t Al[NTERMS == 3 ? 128 * 72 : 1];
  __shared__ ushort_t Bh[128 * 64];                      // XOR-swizzled chunks, no pad
  __shared__ ushort_t Bl[NTERMS == 3 ? 128 * 64 : 1];

  const int tid = threadIdx.x;
  const int lane = tid & 63;
  const int wv = tid >> 6;
  const int wm = wv >> 1, wn = wv & 1;    // 2x2 wave grid
  const int quad = lane >> 4, l15 = lane & 15;
  const int b0 = blockIdx.x * 128;
  const int n0 = blockIdx.y * 128;

  float4v acc[4][4];
#pragma unroll
  for (int a = 0; a < 4; a++)
#pragma unroll
    for (int b = 0; b < 4; b++) acc[a][b] = (float4v)0.0f;

  const int gm = tid >> 1;            // basis-gen: row 0..127
  const int gip = (tid & 1) * 2;      // i-subgroup base (0 or 2) of the 4 per K-step

  const int nsteps = K / 64;
  for (int kstep = 0; kstep < nsteps; ++kstep) {
    const int i0 = kstep * 4;
    __syncthreads();   // previous iteration's reads done before overwrite

    // ---- stage B tile (hi/lo), XOR-swizzle chunk slots: slot = col8 ^ (row&7) ----
#pragma unroll
    for (int c = 0; c < 4; ++c) {
      int chunk = c * 256 + tid;             // 1024 chunks of 8 bf16
      int r = chunk >> 3;                    // 0..127
      int col8 = chunk & 7;
      int slot = col8 ^ (r & 7);
      size_t goff = (size_t)(n0 + r) * K + (size_t)kstep * 64 + col8 * 8;
      *(uint4*)&Bh[r * 64 + slot * 8] = *(const uint4*)&cmh[goff];
      if (NTERMS == 3)
        *(uint4*)&Bl[r * 64 + slot * 8] = *(const uint4*)&cml[goff];
    }

    // ---- generate A tile: 512 x-values -> 4-tap basis, scattered hi/lo ----
    {
      const float2 xv = *(const float2*)&act[(size_t)(b0 + gm) * IN + i0 + gip];
      uint4 z; z.x = z.y = z.z = z.w = 0u;
      ushort_t* arow_h = &Ah[gm * 72 + gip * 16];
      ((uint4*)arow_h)[0] = z; ((uint4*)arow_h)[1] = z;
      ((uint4*)arow_h)[2] = z; ((uint4*)arow_h)[3] = z;
      ushort_t* arow_l = nullptr;
      if (NTERMS == 3) {
        arow_l = &Al[gm * 72 + gip * 16];
        ((uint4*)arow_l)[0] = z; ((uint4*)arow_l)[1] = z;
        ((uint4*)arow_l)[2] = z; ((uint4*)arow_l)[3] = z;
      }
#pragma unroll
      for (int e = 0; e < 2; ++e) {
        int k0; float w[4];
        bspline_w4(e == 0 ? xv.x : xv.y, k0, w);
#pragma unroll
        for (int t = 0; t < 4; ++t) {
          ushort_t h = f2bf(w[t]);
          arow_h[e * 16 + k0 + t] = h;
          if (NTERMS == 3)
            arow_l[e * 16 + k0 + t] = f2bf(w[t] - bf2f(h));
        }
      }
    }
    __syncthreads();

    // ---- MFMA over the two 32-deep halves of BK=64 ----
#pragma unroll
    for (int ks = 0; ks < 2; ++ks) {
      short8 ah[4], al[4], bh[4], bl[4];
#pragma unroll
      for (int mt = 0; mt < 4; ++mt) {
        int off = (wm * 64 + mt * 16 + l15) * 72 + ks * 32 + quad * 8;
        ah[mt] = *(const short8*)&Ah[off];
        if (NTERMS == 3) al[mt] = *(const short8*)&Al[off];
      }
#pragma unroll
      for (int nt = 0; nt < 4; ++nt) {
        int n = wn * 64 + nt * 16 + l15;
        int slot = (ks * 4 + quad) ^ (n & 7);
        int off = n * 64 + slot * 8;
        bh[nt] = *(const short8*)&Bh[off];
        if (NTERMS == 3) bl[nt] = *(const short8*)&Bl[off];
      }
#pragma unroll
      for (int mt = 0; mt < 4; ++mt)
#pragma unroll
        for (int nt = 0; nt < 4; ++nt) {
          if (NTERMS == 3) {
            acc[mt][nt] = __builtin_amdgcn_mfma_f32_16x16x32_bf16(al[mt], bh[nt], acc[mt][nt], 0, 0, 0);
            acc[mt][nt] = __builtin_amdgcn_mfma_f32_16x16x32_bf16(ah[mt], bl[nt], acc[mt][nt], 0, 0, 0);
          }
          acc[mt][nt] = __builtin_amdgcn_mfma_f32_16x16x32_bf16(ah[mt], bh[nt], acc[mt][nt], 0, 0, 0);
        }
    }
  }

  // ---- epilogue: C/D layout col=lane&15, row=quad*4+reg ----
#pragma unroll
  for (int mt = 0; mt < 4; ++mt)
#pragma unroll
    for (int nt = 0; nt < 4; ++nt) {
      int col = n0 + wn * 64 + nt * 16 + l15;
#pragma unroll
      for (int r = 0; r < 4; ++r) {
        int row = b0 + wm * 64 + mt * 16 + quad * 4 + r;
        outp[(size_t)row * OUT + col] = acc[mt][nt][r];
      }
    }
}

// KL accumulation + split-bf16 weight conversion in one pass over cm/lv.
__global__ __launch_bounds__(256) void kl_convert(
    const float* __restrict__ cm, const float* __restrict__ lv,
    ushort_t* __restrict__ ch, ushort_t* __restrict__ cl,
    long long n, float* __restrict__ klout) {
  long long i = (long long)blockIdx.x * blockDim.x + threadIdx.x;
  const long long stride = (long long)gridDim.x * blockDim.x;
  float s = 0.0f;
  for (; i < n; i += stride) {
    float c = cm[i], l = lv[i];
    ushort_t h = f2bf(c);
    ch[i] = h;
    cl[i] = f2bf(c - bf2f(h));
    s += 0.5f * (__expf(l) + c * c - 1.0f - l);
  }
#pragma unroll
  for (int o = 32; o > 0; o >>= 1) s += __shfl_down(s, o, 64);
  __shared__ float red[4];
  int wv = threadIdx.x >> 6;
  if ((threadIdx.x & 63) == 0) red[wv] = s;
  __syncthreads();
  if (threadIdx.x == 0)
    atomicAdd(klout, red[0] + red[1] + red[2] + red[3]);
}

__global__ void zero_kl(float* p) {
  if (threadIdx.x == 0) *p = 0.0f;
}

extern "C" void kernel_launch(void* const* d_in, const int* in_sizes, int n_in,
                              void* d_out, int out_size, void* d_ws, size_t ws_size,
                              hipStream_t stream) {
  const float* x   = (const float*)d_in[0];
  const float* cm0 = (const float*)d_in[1];
  const float* lv0 = (const float*)d_in[2];
  const float* cm1 = (const float*)d_in[3];
  const float* lv1 = (const float*)d_in[4];
  const float* cm2 = (const float*)d_in[5];
  const float* lv2 = (const float*)d_in[6];

  float* out = (float*)d_out;                       // (8192*256) out + 1 KL
  float* klp = out + (size_t)8192 * 256;

  // ws layout (needs 64 MB): acts 2x16MB, split weights 32MB
  char* ws = (char*)d_ws;
  float*    act1 = (float*)(ws);                               // 8192*512 f32
  float*    act2 = (float*)(ws + ((size_t)16 << 20));          // 8192*512 f32
  ushort_t* c0h  = (ushort_t*)(ws + ((size_t)32 << 20));       // 512*256*16
  ushort_t* c0l  = (ushort_t*)(ws + ((size_t)36 << 20));
  ushort_t* c1h  = (ushort_t*)(ws + ((size_t)40 << 20));       // 512*512*16
  ushort_t* c1l  = (ushort_t*)(ws + ((size_t)48 << 20));
  ushort_t* c2h  = (ushort_t*)(ws + ((size_t)56 << 20));       // 256*512*16
  ushort_t* c2l  = (ushort_t*)(ws + ((size_t)60 << 20));

  zero_kl<<<1, 64, 0, stream>>>(klp);
  kl_convert<<<2048, 256, 0, stream>>>(cm0, lv0, c0h, c0l, 512LL * 256 * 16, klp);
  kl_convert<<<2048, 256, 0, stream>>>(cm1, lv1, c1h, c1l, 512LL * 512 * 16, klp);
  kl_convert<<<2048, 256, 0, stream>>>(cm2, lv2, c2h, c2l, 256LL * 512 * 16, klp);

  kan_layer<3><<<dim3(64, 4), 256, 0, stream>>>(x,    c0h, c0l, act1, 256, 512);
  kan_layer<3><<<dim3(64, 4), 256, 0, stream>>>(act1, c1h, c1l, act2, 512, 512);
  kan_layer<1><<<dim3(64, 2), 256, 0, stream>>>(act2, c2h, c2l, out,  512, 256);
}

// Round 2
// 634.704 us; speedup vs baseline: 1.3308x; 1.3308x over previous
//
#include <hip/hip_runtime.h>
#include <hip/hip_bf16.h>

// BayesianKAN: 3 layers of  out[b,o] = sum_{i,k} B-spline-basis(x[b,i])[k] * cm[o,i,k]
// == GEMM (M=8192, N=OUT, K=IN*16) with generated A-operand, plus KL scalar.
// Numerics: downstream amplification ~130x forces split-bf16 (3-term) MFMA for
// layers 0/1; layer 2 (no amplification of its own noise) runs plain bf16.
// R2: split-K (blockIdx.z) + atomicAdd epilogue -> 512 blocks/layer, 2 blocks/CU
// (round 1 had 256 blocks = 1 block/CU, Occupancy 11%, MfmaUtil 24%).

typedef __attribute__((ext_vector_type(8))) short short8;   // 8 bf16 in 4 VGPRs
typedef __attribute__((ext_vector_type(4))) float float4v;  // MFMA accumulator
typedef unsigned short ushort_t;

__device__ __forceinline__ ushort_t f2bf(float f) {
  unsigned u = __float_as_uint(f);
  u += 0x7fffu + ((u >> 16) & 1u);          // round-to-nearest-even
  return (ushort_t)(u >> 16);
}
__device__ __forceinline__ float bf2f(ushort_t h) {
  return __uint_as_float(((unsigned)h) << 16);
}

// Cubic B-spline (n_basis=16, clamped uniform knots: 13 cells of width 1/13).
__device__ __forceinline__ void bspline_w4(float x, int& k0, float w[4]) {
  const float XMAX = 1.0f - 1e-6f;
  float xe = fminf(fmaxf(x, 0.0f), XMAX);
  int cell = (int)(xe * 13.0f);
  cell = cell > 12 ? 12 : cell;
  k0 = cell;
  int j = cell + 3;                 // knot span, 3..15
  const float s = 1.0f / 13.0f;
  int cjm2 = max(j - 5, 0);
  int cjm1 = max(j - 4, 0);
  int cj   = j - 3;
  int cj1  = j - 2;
  int cj2  = min(j - 1, 13);
  int cj3  = min(j, 13);
  float tjm2 = cjm2 * s, tjm1 = cjm1 * s, tj = cj * s;
  float tj1 = cj1 * s, tj2 = cj2 * s, tj3 = cj3 * s;
  float left1 = xe - tj, left2 = xe - tjm1, left3 = xe - tjm2;
  float right1 = tj1 - xe, right2 = tj2 - xe, right3 = tj3 - xe;
#define INV3(d) ((d) == 1 ? 13.0f : ((d) == 2 ? 6.5f : (13.0f / 3.0f)))
  float i10 = INV3(cj1 - cj);
  float i20 = INV3(cj1 - cjm1), i21 = INV3(cj2 - cj);
  float i30 = INV3(cj1 - cjm2), i31 = INV3(cj2 - cjm1), i32 = INV3(cj3 - cj);
#undef INV3
  float temp = i10;
  float N0 = right1 * temp;
  float N1 = left1 * temp;
  temp = N0 * i20;
  N0 = right1 * temp;
  float saved = left2 * temp;
  temp = N1 * i21;
  N1 = saved + right2 * temp;
  float N2 = left1 * temp;
  temp = N0 * i30;
  N0 = right1 * temp;
  saved = left3 * temp;
  temp = N1 * i31;
  N1 = saved + right2 * temp;
  saved = left2 * temp;
  temp = N2 * i32;
  N2 = saved + right3 * temp;
  float N3 = left1 * temp;
  w[0] = N0; w[1] = N1; w[2] = N2; w[3] = N3;
}

// Fused basis-gen + GEMM. Tile 128x128, BK=64 (= 4 input features * 16 basis),
// 256 threads = 4 waves (2x2), wave tile 64x64 (4x4 frags of 16x16x32 bf16).
// blockIdx.z partitions the K-step range; partial sums atomicAdd'ed to outp
// (outp must be pre-zeroed).
template <int NTERMS>
__global__ __launch_bounds__(256) void kan_layer(
    const float* __restrict__ act, const ushort_t* __restrict__ cmh,
    const ushort_t* __restrict__ cml, float* __restrict__ outp,
    int IN, int OUT) {
  const int K = IN * 16;
  __shared__ ushort_t Ah[128 * 72];                      // +8 pad: conflict-free b128 reads
  __shared__ ushort_t Al[NTERMS == 3 ? 128 * 72 : 1];
  __shared__ ushort_t Bh[128 * 64];                      // XOR-swizzled chunks, no pad
  __shared__ ushort_t Bl[NTERMS == 3 ? 128 * 64 : 1];

  const int tid = threadIdx.x;
  const int lane = tid & 63;
  const int wv = tid >> 6;
  const int wm = wv >> 1, wn = wv & 1;    // 2x2 wave grid
  const int quad = lane >> 4, l15 = lane & 15;
  const int b0 = blockIdx.x * 128;
  const int n0 = blockIdx.y * 128;

  float4v acc[4][4];
#pragma unroll
  for (int a = 0; a < 4; a++)
#pragma unroll
    for (int b = 0; b < 4; b++) acc[a][b] = (float4v)0.0f;

  const int gm = tid >> 1;            // basis-gen: row 0..127
  const int gip = (tid & 1) * 2;      // i-subgroup base (0 or 2) of the 4 per K-step

  const int nsteps_total = K / 64;
  const int chunk = nsteps_total / gridDim.z;
  const int kbeg = blockIdx.z * chunk;
  const int kend = kbeg + chunk;
  for (int kstep = kbeg; kstep < kend; ++kstep) {
    const int i0 = kstep * 4;
    __syncthreads();   // previous iteration's reads done before overwrite

    // ---- stage B tile (hi/lo), XOR-swizzle chunk slots: slot = col8 ^ (row&7) ----
#pragma unroll
    for (int c = 0; c < 4; ++c) {
      int chk = c * 256 + tid;               // 1024 chunks of 8 bf16
      int r = chk >> 3;                      // 0..127
      int col8 = chk & 7;
      int slot = col8 ^ (r & 7);
      size_t goff = (size_t)(n0 + r) * K + (size_t)kstep * 64 + col8 * 8;
      *(uint4*)&Bh[r * 64 + slot * 8] = *(const uint4*)&cmh[goff];
      if (NTERMS == 3)
        *(uint4*)&Bl[r * 64 + slot * 8] = *(const uint4*)&cml[goff];
    }

    // ---- generate A tile: 512 x-values -> 4-tap basis, scattered hi/lo ----
    {
      const float2 xv = *(const float2*)&act[(size_t)(b0 + gm) * IN + i0 + gip];
      uint4 z; z.x = z.y = z.z = z.w = 0u;
      ushort_t* arow_h = &Ah[gm * 72 + gip * 16];
      ((uint4*)arow_h)[0] = z; ((uint4*)arow_h)[1] = z;
      ((uint4*)arow_h)[2] = z; ((uint4*)arow_h)[3] = z;
      ushort_t* arow_l = nullptr;
      if (NTERMS == 3) {
        arow_l = &Al[gm * 72 + gip * 16];
        ((uint4*)arow_l)[0] = z; ((uint4*)arow_l)[1] = z;
        ((uint4*)arow_l)[2] = z; ((uint4*)arow_l)[3] = z;
      }
#pragma unroll
      for (int e = 0; e < 2; ++e) {
        int k0; float w[4];
        bspline_w4(e == 0 ? xv.x : xv.y, k0, w);
#pragma unroll
        for (int t = 0; t < 4; ++t) {
          ushort_t h = f2bf(w[t]);
          arow_h[e * 16 + k0 + t] = h;
          if (NTERMS == 3)
            arow_l[e * 16 + k0 + t] = f2bf(w[t] - bf2f(h));
        }
      }
    }
    __syncthreads();

    // ---- MFMA over the two 32-deep halves of BK=64 ----
#pragma unroll
    for (int ks = 0; ks < 2; ++ks) {
      short8 ah[4], al[4], bh[4], bl[4];
#pragma unroll
      for (int mt = 0; mt < 4; ++mt) {
        int off = (wm * 64 + mt * 16 + l15) * 72 + ks * 32 + quad * 8;
        ah[mt] = *(const short8*)&Ah[off];
        if (NTERMS == 3) al[mt] = *(const short8*)&Al[off];
      }
#pragma unroll
      for (int nt = 0; nt < 4; ++nt) {
        int n = wn * 64 + nt * 16 + l15;
        int slot = (ks * 4 + quad) ^ (n & 7);
        int off = n * 64 + slot * 8;
        bh[nt] = *(const short8*)&Bh[off];
        if (NTERMS == 3) bl[nt] = *(const short8*)&Bl[off];
      }
#pragma unroll
      for (int mt = 0; mt < 4; ++mt)
#pragma unroll
        for (int nt = 0; nt < 4; ++nt) {
          if (NTERMS == 3) {
            acc[mt][nt] = __builtin_amdgcn_mfma_f32_16x16x32_bf16(al[mt], bh[nt], acc[mt][nt], 0, 0, 0);
            acc[mt][nt] = __builtin_amdgcn_mfma_f32_16x16x32_bf16(ah[mt], bl[nt], acc[mt][nt], 0, 0, 0);
          }
          acc[mt][nt] = __builtin_amdgcn_mfma_f32_16x16x32_bf16(ah[mt], bh[nt], acc[mt][nt], 0, 0, 0);
        }
    }
  }

  // ---- epilogue: C/D layout col=lane&15, row=quad*4+reg; split-K -> atomicAdd ----
#pragma unroll
  for (int mt = 0; mt < 4; ++mt)
#pragma unroll
    for (int nt = 0; nt < 4; ++nt) {
      int col = n0 + wn * 64 + nt * 16 + l15;
#pragma unroll
      for (int r = 0; r < 4; ++r) {
        int row = b0 + wm * 64 + mt * 16 + quad * 4 + r;
        atomicAdd(&outp[(size_t)row * OUT + col], acc[mt][nt][r]);
      }
    }
}

// KL accumulation + split-bf16 weight conversion in one pass over cm/lv.
__global__ __launch_bounds__(256) void kl_convert(
    const float* __restrict__ cm, const float* __restrict__ lv,
    ushort_t* __restrict__ ch, ushort_t* __restrict__ cl,
    long long n, float* __restrict__ klout) {
  long long i = (long long)blockIdx.x * blockDim.x + threadIdx.x;
  const long long stride = (long long)gridDim.x * blockDim.x;
  float s = 0.0f;
  for (; i < n; i += stride) {
    float c = cm[i], l = lv[i];
    ushort_t h = f2bf(c);
    ch[i] = h;
    cl[i] = f2bf(c - bf2f(h));
    s += 0.5f * (__expf(l) + c * c - 1.0f - l);
  }
#pragma unroll
  for (int o = 32; o > 0; o >>= 1) s += __shfl_down(s, o, 64);
  __shared__ float red[4];
  int wv = threadIdx.x >> 6;
  if ((threadIdx.x & 63) == 0) red[wv] = s;
  __syncthreads();
  if (threadIdx.x == 0)
    atomicAdd(klout, red[0] + red[1] + red[2] + red[3]);
}

__global__ __launch_bounds__(256) void zero_buf(float* __restrict__ p, long long n) {
  long long i = (long long)blockIdx.x * blockDim.x + threadIdx.x;
  const long long stride = (long long)gridDim.x * blockDim.x;
  for (; i < n; i += stride) p[i] = 0.0f;
}

extern "C" void kernel_launch(void* const* d_in, const int* in_sizes, int n_in,
                              void* d_out, int out_size, void* d_ws, size_t ws_size,
                              hipStream_t stream) {
  const float* x   = (const float*)d_in[0];
  const float* cm0 = (const float*)d_in[1];
  const float* lv0 = (const float*)d_in[2];
  const float* cm1 = (const float*)d_in[3];
  const float* lv1 = (const float*)d_in[4];
  const float* cm2 = (const float*)d_in[5];
  const float* lv2 = (const float*)d_in[6];

  float* out = (float*)d_out;                       // (8192*256) out + 1 KL
  float* klp = out + (size_t)8192 * 256;

  // ws layout (needs 64 MB): acts 2x16MB, split weights 32MB
  char* ws = (char*)d_ws;
  float*    act1 = (float*)(ws);                               // 8192*512 f32
  float*    act2 = (float*)(ws + ((size_t)16 << 20));          // 8192*512 f32
  ushort_t* c0h  = (ushort_t*)(ws + ((size_t)32 << 20));       // 512*256*16
  ushort_t* c0l  = (ushort_t*)(ws + ((size_t)36 << 20));
  ushort_t* c1h  = (ushort_t*)(ws + ((size_t)40 << 20));       // 512*512*16
  ushort_t* c1l  = (ushort_t*)(ws + ((size_t)48 << 20));
  ushort_t* c2h  = (ushort_t*)(ws + ((size_t)56 << 20));       // 256*512*16
  ushort_t* c2l  = (ushort_t*)(ws + ((size_t)60 << 20));

  // zero split-K accumulation targets: act1+act2 (contiguous) and d_out (incl KL)
  zero_buf<<<1024, 256, 0, stream>>>(act1, 2LL * 8192 * 512);
  zero_buf<<<1024, 256, 0, stream>>>(out, (long long)out_size);

  kl_convert<<<2048, 256, 0, stream>>>(cm0, lv0, c0h, c0l, 512LL * 256 * 16, klp);
  kl_convert<<<2048, 256, 0, stream>>>(cm1, lv1, c1h, c1l, 512LL * 512 * 16, klp);
  kl_convert<<<2048, 256, 0, stream>>>(cm2, lv2, c2h, c2l, 256LL * 512 * 16, klp);

  // split-K grids: 512 blocks each -> 2 blocks/CU (LDS 69632B x2 < 160KB)
  kan_layer<3><<<dim3(64, 4, 2), 256, 0, stream>>>(x,    c0h, c0l, act1, 256, 512);
  kan_layer<3><<<dim3(64, 4, 2), 256, 0, stream>>>(act1, c1h, c1l, act2, 512, 512);
  kan_layer<1><<<dim3(64, 2, 4), 256, 0, stream>>>(act2, c2h, c2l, out,  512, 256);
}